// Round 1
// baseline (1810.125 us; speedup 1.0000x reference)
//
#include <hip/hip_runtime.h>
#include <math.h>

#define BATCH 4096
#define T 128
#define HOR 24
#define EH 64
#define DH 64
#define A 32

__global__ __launch_bounds__(256, 2)
void darnn_kernel(const float* __restrict__ x,
                  const float* __restrict__ W_ih_e, const float* __restrict__ W_hh_e,
                  const float* __restrict__ b_ih_e, const float* __restrict__ b_hh_e,
                  const float* __restrict__ W_init, const float* __restrict__ b_init,
                  const float* __restrict__ W_ih_d, const float* __restrict__ W_hh_d,
                  const float* __restrict__ b_ih_d, const float* __restrict__ b_hh_d,
                  const float* __restrict__ W_d, const float* __restrict__ U_d,
                  const float* __restrict__ v_d, const float* __restrict__ W_out,
                  const float* __restrict__ b_out, const float* __restrict__ y0,
                  float* __restrict__ out)
{
  const int tid = threadIdx.x;
  const int b = blockIdx.x;

  __shared__ float sh_x[T];
  __shared__ float sh_h[EH];
  __shared__ float sh_d[DH];
  __shared__ float sh_gh[3*EH];
  __shared__ float sh_H[T][EH];        // encoder states, 32 KB
  __shared__ float sh_Hp[T*(A+1)];     // H_proj, pad 33 to kill bank conflicts
  __shared__ float sh_s[T];            // scores -> beta
  __shared__ float sh_red[4];
  __shared__ float sh_part[128];
  __shared__ float sh_dp[A];
  __shared__ float sh_WdT[EH][A];      // W_d transposed, 8 KB
  __shared__ float sh_wih[3*EH];
  __shared__ float sh_bih[3*EH];
  __shared__ float sh_bhh[3*EH];
  __shared__ float sh_vd[A];
  __shared__ float sh_wout[DH+EH];
  __shared__ float sh_scal[2];         // [0]=dec_in, [1]=b_out

  float wrow[64];                      // W_hh row (enc), then U_d row, then W_hh row (dec)

  // ---------------- stage ----------------
  if (tid < 192) {
    sh_wih[tid] = W_ih_e[tid];
    sh_bih[tid] = b_ih_e[tid];
    sh_bhh[tid] = b_hh_e[tid];
  }
  if (tid < T)  sh_x[tid] = x[b*T + tid];
  if (tid < EH) sh_h[tid] = 0.0f;
  for (int idx = tid; idx < A*EH; idx += 256) {
    int a = idx >> 6, e = idx & 63;
    sh_WdT[e][a] = W_d[idx];           // one-time transpose
  }
  if (tid < 192) {
    const float4* src = (const float4*)(W_hh_e + tid*64);
    #pragma unroll
    for (int k = 0; k < 16; ++k) {
      float4 v = src[k];
      wrow[4*k+0]=v.x; wrow[4*k+1]=v.y; wrow[4*k+2]=v.z; wrow[4*k+3]=v.w;
    }
  }
  __syncthreads();

  // ---------------- encoder: 128 sequential GRU steps ----------------
  // NOTE: encoder input-attention is a no-op (softmax over size-1 axis == 1),
  // so the GRU input is x_t directly; W_e/U_e/b_e/v_e are dead.
  for (int t = 0; t < T; ++t) {
    if (tid < 192) {
      float acc = sh_bhh[tid];
      #pragma unroll
      for (int k = 0; k < 64; ++k) acc = fmaf(wrow[k], sh_h[k], acc);
      sh_gh[tid] = acc;
    }
    __syncthreads();
    if (tid < EH) {
      float xt = sh_x[t];
      float ir = fmaf(xt, sh_wih[tid],      sh_bih[tid]);
      float iz = fmaf(xt, sh_wih[64+tid],   sh_bih[64+tid]);
      float in_= fmaf(xt, sh_wih[128+tid],  sh_bih[128+tid]);
      float r = 1.0f/(1.0f + expf(-(ir + sh_gh[tid])));
      float z = 1.0f/(1.0f + expf(-(iz + sh_gh[64+tid])));
      float n = tanhf(in_ + r*sh_gh[128+tid]);
      float hnew = (1.0f - z)*n + z*sh_h[tid];
      sh_h[tid] = hnew;
      sh_H[t][tid] = hnew;
    }
    __syncthreads();
  }

  // ---------------- decoder prep ----------------
  if (tid < 192) {
    sh_wih[tid] = W_ih_d[tid];
    sh_bih[tid] = b_ih_d[tid];
    sh_bhh[tid] = b_hh_d[tid];
  }
  if (tid < DH+EH) sh_wout[tid] = W_out[tid];
  if (tid < A)     sh_vd[tid]   = v_d[tid];
  if (tid == 0) { sh_scal[0] = y0[0]; sh_scal[1] = b_out[0]; }
  if (tid < DH) {                      // d0 = h_T @ W_init.T + b_init
    const float4* wi = (const float4*)(W_init + tid*64);
    float acc = b_init[tid];
    #pragma unroll
    for (int k = 0; k < 16; ++k) {
      float4 v = wi[k];
      acc += v.x*sh_h[4*k] + v.y*sh_h[4*k+1] + v.z*sh_h[4*k+2] + v.w*sh_h[4*k+3];
    }
    sh_d[tid] = acc;
  }
  // H_proj[t][a] = sum_e U_d[a][e] * H[t][e]; thread's a = tid&31 fixed
  {
    const float4* us = (const float4*)(U_d + (tid & 31)*64);
    #pragma unroll
    for (int k = 0; k < 16; ++k) {
      float4 v = us[k];
      wrow[4*k+0]=v.x; wrow[4*k+1]=v.y; wrow[4*k+2]=v.z; wrow[4*k+3]=v.w;
    }
  }
  for (int kk = 0; kk < 16; ++kk) {
    int t = (tid >> 5) + kk*8;
    float acc = 0.0f;
    #pragma unroll
    for (int e = 0; e < 64; ++e) acc = fmaf(wrow[e], sh_H[t][e], acc);
    sh_Hp[t*(A+1) + (tid & 31)] = acc;
  }
  if (tid < 192) {                     // reload wrow with decoder W_hh rows
    const float4* src = (const float4*)(W_hh_d + tid*64);
    #pragma unroll
    for (int k = 0; k < 16; ++k) {
      float4 v = src[k];
      wrow[4*k+0]=v.x; wrow[4*k+1]=v.y; wrow[4*k+2]=v.z; wrow[4*k+3]=v.w;
    }
  }
  __syncthreads();

  // ---------------- decoder: 24 sequential steps ----------------
  for (int s = 0; s < HOR; ++s) {
    // GRU matvec
    if (tid < 192) {
      float acc = sh_bhh[tid];
      #pragma unroll
      for (int k = 0; k < 64; ++k) acc = fmaf(wrow[k], sh_d[k], acc);
      sh_gh[tid] = acc;
    }
    __syncthreads();
    // GRU combine
    if (tid < DH) {
      float xt = sh_scal[0];
      float ir = fmaf(xt, sh_wih[tid],     sh_bih[tid]);
      float iz = fmaf(xt, sh_wih[64+tid],  sh_bih[64+tid]);
      float in_= fmaf(xt, sh_wih[128+tid], sh_bih[128+tid]);
      float r = 1.0f/(1.0f + expf(-(ir + sh_gh[tid])));
      float z = 1.0f/(1.0f + expf(-(iz + sh_gh[64+tid])));
      float n = tanhf(in_ + r*sh_gh[128+tid]);
      sh_d[tid] = (1.0f - z)*n + z*sh_d[tid];
    }
    __syncthreads();
    // d_proj = W_d @ d : 128 threads, (a, quarter-of-k) partials
    if (tid < 128) {
      int a = tid & 31, q = tid >> 5;
      float acc = 0.0f;
      #pragma unroll
      for (int e = 0; e < 16; ++e)
        acc = fmaf(sh_WdT[q*16+e][a], sh_d[q*16+e], acc);
      sh_part[tid] = acc;
    }
    __syncthreads();
    if (tid < A)
      sh_dp[tid] = sh_part[tid] + sh_part[32+tid] + sh_part[64+tid] + sh_part[96+tid];
    __syncthreads();
    // scores[t] = sum_a v_d[a]*tanh(d_proj[a] + H_proj[t][a])
    float myexp = 0.0f;
    if (tid < T) {
      float accs = 0.0f;
      #pragma unroll
      for (int a = 0; a < A; ++a) {
        float v = tanhf(sh_dp[a] + sh_Hp[tid*(A+1)+a]);
        accs = fmaf(v, sh_vd[a], accs);
      }
      sh_s[tid] = accs;
      float m = accs;
      #pragma unroll
      for (int off = 32; off > 0; off >>= 1) m = fmaxf(m, __shfl_xor(m, off));
      if ((tid & 63) == 0) sh_red[tid >> 6] = m;
    }
    __syncthreads();
    // softmax: exp + sum
    if (tid < T) {
      float m = fmaxf(sh_red[0], sh_red[1]);
      float ex = expf(sh_s[tid] - m);
      myexp = ex;
      float ss = ex;
      #pragma unroll
      for (int off = 32; off > 0; off >>= 1) ss += __shfl_xor(ss, off);
      if ((tid & 63) == 0) sh_red[2 + (tid >> 6)] = ss;
    }
    __syncthreads();
    if (tid < T)
      sh_s[tid] = myexp * (1.0f / (sh_red[2] + sh_red[3]));
    __syncthreads();
    // ctx[e] = sum_t beta[t]*H[t][e] : 128 threads, (e, half-of-t) partials
    if (tid < 128) {
      int e = tid & 63, half = tid >> 6;
      float acc = 0.0f;
      #pragma unroll
      for (int tt = 0; tt < 64; ++tt) {
        int t = half*64 + tt;
        acc = fmaf(sh_s[t], sh_H[t][e], acc);
      }
      sh_part[tid] = acc;
    }
    __syncthreads();
    // out = [d, ctx] @ W_out.T + b_out ; wave-0 reduce
    if (tid < 64) {
      float ctx = sh_part[tid] + sh_part[64+tid];
      float pe = sh_wout[tid]*sh_d[tid] + sh_wout[64+tid]*ctx;
      #pragma unroll
      for (int off = 32; off > 0; off >>= 1) pe += __shfl_xor(pe, off);
      if (tid == 0) {
        float o = pe + sh_scal[1];
        out[b*HOR + s] = o;
        sh_scal[0] = o;    // feeds next step's GRU input
      }
    }
    __syncthreads();
  }
}

extern "C" void kernel_launch(void* const* d_in, const int* in_sizes, int n_in,
                              void* d_out, int out_size, void* d_ws, size_t ws_size,
                              hipStream_t stream) {
  const float* x      = (const float*)d_in[0];
  const float* W_ih_e = (const float*)d_in[1];
  const float* W_hh_e = (const float*)d_in[2];
  const float* b_ih_e = (const float*)d_in[3];
  const float* b_hh_e = (const float*)d_in[4];
  // d_in[5..8] = W_e, U_e, b_e, v_e : dead (softmax over size-1 axis == 1)
  const float* W_init = (const float*)d_in[9];
  const float* b_init = (const float*)d_in[10];
  const float* W_ih_d = (const float*)d_in[11];
  const float* W_hh_d = (const float*)d_in[12];
  const float* b_ih_d = (const float*)d_in[13];
  const float* b_hh_d = (const float*)d_in[14];
  const float* W_d    = (const float*)d_in[15];
  const float* U_d    = (const float*)d_in[16];
  const float* v_d    = (const float*)d_in[17];
  const float* W_out  = (const float*)d_in[18];
  const float* b_out  = (const float*)d_in[19];
  const float* y0     = (const float*)d_in[20];
  float* outp = (float*)d_out;

  darnn_kernel<<<BATCH, 256, 0, stream>>>(x, W_ih_e, W_hh_e, b_ih_e, b_hh_e,
      W_init, b_init, W_ih_d, W_hh_d, b_ih_d, b_hh_d, W_d, U_d, v_d, W_out,
      b_out, y0, outp);
}

// Round 2
// 1017.063 us; speedup vs baseline: 1.7798x; 1.7798x over previous
//
#include <hip/hip_runtime.h>
#include <math.h>

#define BATCH 4096
#define T 128
#define HOR 24
#define EH 64
#define DH 64
#define A 32

#define LOG2E 1.44269504088896f

__device__ __forceinline__ float fexp(float x) {
  return __builtin_amdgcn_exp2f(x * LOG2E);
}
__device__ __forceinline__ float fsig(float x) {
  return __builtin_amdgcn_rcpf(1.0f + __builtin_amdgcn_exp2f(-LOG2E * x));
}
__device__ __forceinline__ float ftanh(float x) {
  // tanh(x) = 1 - 2/(1+e^{2x}); saturates correctly at +-inf
  return fmaf(-2.0f, __builtin_amdgcn_rcpf(1.0f + __builtin_amdgcn_exp2f(2.0f * LOG2E * x)), 1.0f);
}

__global__ __launch_bounds__(256, 3)
void darnn_kernel(const float* __restrict__ x,
                  const float* __restrict__ W_ih_e, const float* __restrict__ W_hh_e,
                  const float* __restrict__ b_ih_e, const float* __restrict__ b_hh_e,
                  const float* __restrict__ W_init, const float* __restrict__ b_init,
                  const float* __restrict__ W_ih_d, const float* __restrict__ W_hh_d,
                  const float* __restrict__ b_ih_d, const float* __restrict__ b_hh_d,
                  const float* __restrict__ W_d, const float* __restrict__ U_d,
                  const float* __restrict__ v_d, const float* __restrict__ W_out,
                  const float* __restrict__ b_out, const float* __restrict__ y0,
                  float* __restrict__ out)
{
  const int tid = threadIdx.x;
  const int b = blockIdx.x;

  __shared__ float sh_x[T];
  __shared__ float sh_h[EH];
  __shared__ float sh_d[DH];
  __shared__ float sh_gh[3*EH];
  __shared__ float sh_H[T][EH];          // 32 KB
  __shared__ float sh_s[T];
  __shared__ float sh_dp[A];
  __shared__ float sh_wih[3*EH];
  __shared__ float sh_bih[3*EH];
  __shared__ float sh_bhh[3*EH];
  __shared__ float sh_vd[A];
  __shared__ float sh_wout[DH+EH];
  __shared__ float sh_red[4];
  __shared__ float sh_scal[2];           // [0]=dec_in, [1]=b_out
  __shared__ float sh_scratch[1056];     // ctx partials (16*64) / Hp chunk (32*33)

  float4 wr[16];                         // one 64-float weight row
  float  hp[A];                          // H_proj row t=tid (tid<128)

  // ---------------- stage ----------------
  if (tid < 192) {
    sh_wih[tid] = W_ih_e[tid];
    sh_bih[tid] = b_ih_e[tid];
    sh_bhh[tid] = b_hh_e[tid];
    const float4* src = (const float4*)(W_hh_e + tid*64);
    #pragma unroll
    for (int k = 0; k < 16; ++k) wr[k] = src[k];
  }
  if (tid < T)  sh_x[tid] = x[b*T + tid];
  if (tid < EH) sh_h[tid] = 0.0f;
  __syncthreads();

  // ---------------- encoder: 128 sequential GRU steps ----------------
  // encoder input-attention is identity (softmax over size-1 axis == 1).
  for (int t = 0; t < T; ++t) {
    if (tid < 192) {
      const float4* h4 = (const float4*)sh_h;
      float a0 = 0.f, a1 = 0.f, a2 = 0.f, a3 = 0.f;
      #pragma unroll
      for (int k = 0; k < 16; ++k) {
        float4 hv = h4[k];
        a0 = fmaf(wr[k].x, hv.x, a0);
        a1 = fmaf(wr[k].y, hv.y, a1);
        a2 = fmaf(wr[k].z, hv.z, a2);
        a3 = fmaf(wr[k].w, hv.w, a3);
      }
      sh_gh[tid] = sh_bhh[tid] + ((a0 + a1) + (a2 + a3));
    }
    __syncthreads();
    if (tid < EH) {
      float xt = sh_x[t];
      float ir = fmaf(xt, sh_wih[tid],     sh_bih[tid]);
      float iz = fmaf(xt, sh_wih[64+tid],  sh_bih[64+tid]);
      float in_= fmaf(xt, sh_wih[128+tid], sh_bih[128+tid]);
      float r = fsig(ir + sh_gh[tid]);
      float z = fsig(iz + sh_gh[64+tid]);
      float n = ftanh(in_ + r*sh_gh[128+tid]);
      float hnew = fmaf(z, sh_h[tid] - n, n);   // (1-z)n + z*h
      sh_h[tid] = hnew;
      sh_H[t][tid] = hnew;
    }
    __syncthreads();
  }

  // ---------------- decoder prep ----------------
  if (tid < 192) {
    sh_wih[tid] = W_ih_d[tid];
    sh_bih[tid] = b_ih_d[tid];
    sh_bhh[tid] = b_hh_d[tid];
  }
  if (tid < DH+EH) sh_wout[tid] = W_out[tid];
  if (tid < A)     sh_vd[tid]   = v_d[tid];
  if (tid == 0) { sh_scal[0] = y0[0]; sh_scal[1] = b_out[0]; }
  if (tid < DH) {                        // d0 = h_T @ W_init.T + b_init
    const float4* wi = (const float4*)(W_init + tid*64);
    const float4* h4 = (const float4*)sh_h;
    float a0 = 0.f, a1 = 0.f, a2 = 0.f, a3 = 0.f;
    #pragma unroll
    for (int k = 0; k < 16; ++k) {
      float4 wv = wi[k]; float4 hv = h4[k];
      a0 = fmaf(wv.x, hv.x, a0);
      a1 = fmaf(wv.y, hv.y, a1);
      a2 = fmaf(wv.z, hv.z, a2);
      a3 = fmaf(wv.w, hv.w, a3);
    }
    sh_d[tid] = b_init[tid] + ((a0 + a1) + (a2 + a3));
  }

  // H_proj rows -> registers. All 256 threads hold U_d row (tid&31).
  {
    const float4* us = (const float4*)(U_d + (tid & 31)*64);
    #pragma unroll
    for (int k = 0; k < 16; ++k) wr[k] = us[k];
  }
  __syncthreads();
  #pragma unroll
  for (int c = 0; c < 4; ++c) {          // chunks of 32 t-rows
    #pragma unroll
    for (int r = 0; r < 4; ++r) {
      int tl = (tid >> 5)*4 + r;         // 0..31
      int t  = c*32 + tl;
      const float4* H4 = (const float4*)sh_H[t];
      float a0 = 0.f, a1 = 0.f, a2 = 0.f, a3 = 0.f;
      #pragma unroll
      for (int k = 0; k < 16; ++k) {
        float4 hv = H4[k];
        a0 = fmaf(wr[k].x, hv.x, a0);
        a1 = fmaf(wr[k].y, hv.y, a1);
        a2 = fmaf(wr[k].z, hv.z, a2);
        a3 = fmaf(wr[k].w, hv.w, a3);
      }
      sh_scratch[tl*33 + (tid & 31)] = (a0 + a1) + (a2 + a3);
    }
    __syncthreads();
    int tl = tid - c*32;
    if (tl >= 0 && tl < 32) {            // owner thread t = tid (tid<128)
      #pragma unroll
      for (int a = 0; a < A; ++a) hp[a] = sh_scratch[tl*33 + a];
    }
    __syncthreads();
  }

  // reload wr: decoder W_hh rows (tid<192), W_d rows (tid 192..223)
  if (tid < 192) {
    const float4* src = (const float4*)(W_hh_d + tid*64);
    #pragma unroll
    for (int k = 0; k < 16; ++k) wr[k] = src[k];
  } else if (tid < 224) {
    const float4* src = (const float4*)(W_d + (tid-192)*64);
    #pragma unroll
    for (int k = 0; k < 16; ++k) wr[k] = src[k];
  }
  __syncthreads();

  // prologue GRU matvec for step 0
  if (tid < 192) {
    const float4* d4 = (const float4*)sh_d;
    float a0 = 0.f, a1 = 0.f, a2 = 0.f, a3 = 0.f;
    #pragma unroll
    for (int k = 0; k < 16; ++k) {
      float4 dv = d4[k];
      a0 = fmaf(wr[k].x, dv.x, a0);
      a1 = fmaf(wr[k].y, dv.y, a1);
      a2 = fmaf(wr[k].z, dv.z, a2);
      a3 = fmaf(wr[k].w, dv.w, a3);
    }
    sh_gh[tid] = sh_bhh[tid] + ((a0 + a1) + (a2 + a3));
  }
  __syncthreads();

  // ---------------- decoder: 24 sequential steps, 5 barriers each -------
  for (int s = 0; s < HOR; ++s) {
    // (1) GRU combine -> new d
    if (tid < DH) {
      float xt = sh_scal[0];
      float ir = fmaf(xt, sh_wih[tid],     sh_bih[tid]);
      float iz = fmaf(xt, sh_wih[64+tid],  sh_bih[64+tid]);
      float in_= fmaf(xt, sh_wih[128+tid], sh_bih[128+tid]);
      float r = fsig(ir + sh_gh[tid]);
      float z = fsig(iz + sh_gh[64+tid]);
      float n = ftanh(in_ + r*sh_gh[128+tid]);
      sh_d[tid] = fmaf(z, sh_d[tid] - n, n);
    }
    __syncthreads();
    // (2) next-step GRU matvec (tid<192) || d_proj (tid 192..223)
    if (tid < 192) {
      const float4* d4 = (const float4*)sh_d;
      float a0 = 0.f, a1 = 0.f, a2 = 0.f, a3 = 0.f;
      #pragma unroll
      for (int k = 0; k < 16; ++k) {
        float4 dv = d4[k];
        a0 = fmaf(wr[k].x, dv.x, a0);
        a1 = fmaf(wr[k].y, dv.y, a1);
        a2 = fmaf(wr[k].z, dv.z, a2);
        a3 = fmaf(wr[k].w, dv.w, a3);
      }
      sh_gh[tid] = sh_bhh[tid] + ((a0 + a1) + (a2 + a3));
    } else if (tid < 224) {
      const float4* d4 = (const float4*)sh_d;
      float a0 = 0.f, a1 = 0.f, a2 = 0.f, a3 = 0.f;
      #pragma unroll
      for (int k = 0; k < 16; ++k) {
        float4 dv = d4[k];
        a0 = fmaf(wr[k].x, dv.x, a0);
        a1 = fmaf(wr[k].y, dv.y, a1);
        a2 = fmaf(wr[k].z, dv.z, a2);
        a3 = fmaf(wr[k].w, dv.w, a3);
      }
      sh_dp[tid-192] = (a0 + a1) + (a2 + a3);
    }
    __syncthreads();
    // (3) scores + exp + per-wave sum (no max-sub: |s| <= sum|v_d| ~ 2.6)
    if (tid < T) {
      const float4* dp4 = (const float4*)sh_dp;
      const float4* vd4 = (const float4*)sh_vd;
      float acc = 0.f;
      #pragma unroll
      for (int a4 = 0; a4 < 8; ++a4) {
        float4 dp = dp4[a4]; float4 vd = vd4[a4];
        acc = fmaf(ftanh(dp.x + hp[4*a4+0]), vd.x, acc);
        acc = fmaf(ftanh(dp.y + hp[4*a4+1]), vd.y, acc);
        acc = fmaf(ftanh(dp.z + hp[4*a4+2]), vd.z, acc);
        acc = fmaf(ftanh(dp.w + hp[4*a4+3]), vd.w, acc);
      }
      float ex = fexp(acc);
      sh_s[tid] = ex;
      float ss = ex;
      #pragma unroll
      for (int off = 32; off > 0; off >>= 1) ss += __shfl_xor(ss, off);
      if ((tid & 63) == 0) sh_red[tid >> 6] = ss;
    }
    __syncthreads();
    // (4) ctx partials: 256 threads, 16 t-groups x 16 e-quads
    {
      int tq = tid >> 4;                 // 0..15
      int e4 = (tid & 15) * 4;
      float4 acc = make_float4(0.f, 0.f, 0.f, 0.f);
      #pragma unroll
      for (int tt = 0; tt < 8; ++tt) {
        int t = tq*8 + tt;
        float svt = sh_s[t];
        float4 hv = *(const float4*)&sh_H[t][e4];
        acc.x = fmaf(svt, hv.x, acc.x);
        acc.y = fmaf(svt, hv.y, acc.y);
        acc.z = fmaf(svt, hv.z, acc.z);
        acc.w = fmaf(svt, hv.w, acc.w);
      }
      *(float4*)&sh_scratch[tq*64 + e4] = acc;
    }
    __syncthreads();
    // (5) output: reduce ctx, project, write, feed back
    if (tid < 64) {
      float ctxv = 0.f;
      #pragma unroll
      for (int q = 0; q < 16; ++q) ctxv += sh_scratch[q*64 + tid];
      float invS = __builtin_amdgcn_rcpf(sh_red[0] + sh_red[1]);
      float pe = sh_wout[tid]*sh_d[tid] + sh_wout[64+tid]*ctxv*invS;
      #pragma unroll
      for (int off = 32; off > 0; off >>= 1) pe += __shfl_xor(pe, off);
      if (tid == 0) {
        float o = pe + sh_scal[1];
        out[b*HOR + s] = o;
        sh_scal[0] = o;
      }
    }
    __syncthreads();
  }
}

extern "C" void kernel_launch(void* const* d_in, const int* in_sizes, int n_in,
                              void* d_out, int out_size, void* d_ws, size_t ws_size,
                              hipStream_t stream) {
  const float* x      = (const float*)d_in[0];
  const float* W_ih_e = (const float*)d_in[1];
  const float* W_hh_e = (const float*)d_in[2];
  const float* b_ih_e = (const float*)d_in[3];
  const float* b_hh_e = (const float*)d_in[4];
  // d_in[5..8] = W_e, U_e, b_e, v_e : dead (softmax over size-1 axis == 1)
  const float* W_init = (const float*)d_in[9];
  const float* b_init = (const float*)d_in[10];
  const float* W_ih_d = (const float*)d_in[11];
  const float* W_hh_d = (const float*)d_in[12];
  const float* b_ih_d = (const float*)d_in[13];
  const float* b_hh_d = (const float*)d_in[14];
  const float* W_d    = (const float*)d_in[15];
  const float* U_d    = (const float*)d_in[16];
  const float* v_d    = (const float*)d_in[17];
  const float* W_out  = (const float*)d_in[18];
  const float* b_out  = (const float*)d_in[19];
  const float* y0     = (const float*)d_in[20];
  float* outp = (float*)d_out;

  darnn_kernel<<<BATCH, 256, 0, stream>>>(x, W_ih_e, W_hh_e, b_ih_e, b_hh_e,
      W_init, b_init, W_ih_d, W_hh_d, b_ih_d, b_hh_d, W_d, U_d, v_d, W_out,
      b_out, y0, outp);
}

// Round 3
// 554.501 us; speedup vs baseline: 3.2644x; 1.8342x over previous
//
#include <hip/hip_runtime.h>
#include <math.h>

#define BATCH 4096
#define T 128
#define HOR 24
#define EH 64
#define DH 64
#define A 32

#define LOG2E 1.44269504088896f

typedef _Float16 half2_t __attribute__((ext_vector_type(2)));

__device__ __forceinline__ float fexp(float x) {
  return __builtin_amdgcn_exp2f(x * LOG2E);
}
__device__ __forceinline__ float fsig(float x) {
  return __builtin_amdgcn_rcpf(1.0f + __builtin_amdgcn_exp2f(-LOG2E * x));
}
__device__ __forceinline__ float ftanh(float x) {
  return fmaf(-2.0f, __builtin_amdgcn_rcpf(1.0f + __builtin_amdgcn_exp2f(2.0f * LOG2E * x)), 1.0f);
}
__device__ __forceinline__ half2_t bch(unsigned u) {
  return __builtin_bit_cast(half2_t, u);
}
__device__ __forceinline__ float fdot2f(half2_t a, half2_t b, float c) {
#if __has_builtin(__builtin_amdgcn_fdot2)
  return __builtin_amdgcn_fdot2(a, b, c, false);
#else
  return fmaf((float)a.x, (float)b.x, fmaf((float)a.y, (float)b.y, c));
#endif
}
__device__ __forceinline__ float wredsum(float v) {
  #pragma unroll
  for (int o = 32; o > 0; o >>= 1) v += __shfl_xor(v, o);
  return v;
}

// One wave per batch element. Lane i owns h[i]/d[i] and W_hh rows i,64+i,128+i
// in VGPRs. No inter-wave synchronization anywhere: blockDim=64.
__global__ __launch_bounds__(64, 2)
void darnn_kernel(const float* __restrict__ x,
                  const float* __restrict__ W_ih_e, const float* __restrict__ W_hh_e,
                  const float* __restrict__ b_ih_e, const float* __restrict__ b_hh_e,
                  const float* __restrict__ W_init, const float* __restrict__ b_init,
                  const float* __restrict__ W_ih_d, const float* __restrict__ W_hh_d,
                  const float* __restrict__ b_ih_d, const float* __restrict__ b_hh_d,
                  const float* __restrict__ W_d, const float* __restrict__ U_d,
                  const float* __restrict__ v_d, const float* __restrict__ W_out,
                  const float* __restrict__ b_out, const float* __restrict__ y0,
                  float* __restrict__ out)
{
  const int l = threadIdx.x;          // 0..63
  const int b = blockIdx.x;
  const int a    = l & 31;            // attention index owned by this lane
  const int half = l >> 5;            // which half of the 64-dim dot

  __shared__ __align__(16) float     sh_h[EH];        // 256 B
  __shared__ __align__(16) _Float16  sh_h16[EH];      // 128 B
  __shared__ __align__(16) float     sh_d[DH];        // 256 B
  __shared__ __align__(16) _Float16  sh_d16[DH];      // 128 B
  __shared__ __align__(16) float     sh_x[T];         // 512 B
  __shared__ __align__(16) float     sh_hw[T];        // 512 B  hw[t]=W_out2.h_t
  __shared__ __align__(16) float     sh_dp[A];        // 128 B
  __shared__ __align__(16) unsigned  sh_hp[T][17];    // 8704 B Hp fp16-packed (pad 17)
  __shared__ __align__(16) unsigned  sh_ud[16][64];   // 4096 B U_d (later W_d) half2, transposed

  float4 wr[48];                      // W_hh rows i / 64+i / 128+i

  // ---------------- stage ----------------
  {
    const float4* wp = (const float4*)W_hh_e;
    #pragma unroll
    for (int k = 0; k < 16; ++k) {
      wr[k]      = wp[(l      ) * 16 + k];
      wr[16 + k] = wp[(64 + l ) * 16 + k];
      wr[32 + k] = wp[(128 + l) * 16 + k];
    }
  }
  float wih0 = W_ih_e[l], wih1 = W_ih_e[64 + l], wih2 = W_ih_e[128 + l];
  float bih0 = b_ih_e[l], bih1 = b_ih_e[64 + l], bih2 = b_ih_e[128 + l];
  float bhh0 = b_hh_e[l], bhh1 = b_hh_e[64 + l], bhh2 = b_hh_e[128 + l];
  float wout1 = W_out[l], wout2 = W_out[64 + l];
  {
    float2 g = ((const float2*)(x + (size_t)b * T))[l];
    *(float2*)&sh_x[2 * l] = g;
  }
  sh_h[l] = 0.0f;
  sh_h16[l] = (_Float16)0.0f;
  {  // U_d -> sh_ud[k][lane]: lane l holds row a, half `half`, packed half2
    const float2* up = (const float2*)(U_d + a * 64 + half * 32);
    #pragma unroll
    for (int k = 0; k < 16; ++k) {
      float2 f = up[k];
      sh_ud[k][l] = __builtin_bit_cast(unsigned, __builtin_amdgcn_cvt_pkrtz(f.x, f.y));
    }
  }
  __syncthreads();

  // ---------------- encoder: 128 steps, fully in one wave ----------------
  // input-attention is identity (softmax over size-1 axis == 1).
  float hprev = 0.0f;
  for (int t = 0; t < T; ++t) {
    float gr0 = bhh0, gr1 = 0.f, gz0 = bhh1, gz1 = 0.f, gn0 = bhh2, gn1 = 0.f;
    #pragma unroll
    for (int k = 0; k < 16; ++k) {
      float4 hv = *(const float4*)&sh_h[4 * k];
      float4 w0 = wr[k], w1 = wr[16 + k], w2 = wr[32 + k];
      gr0 = fmaf(w0.x, hv.x, gr0); gr1 = fmaf(w0.y, hv.y, gr1);
      gr0 = fmaf(w0.z, hv.z, gr0); gr1 = fmaf(w0.w, hv.w, gr1);
      gz0 = fmaf(w1.x, hv.x, gz0); gz1 = fmaf(w1.y, hv.y, gz1);
      gz0 = fmaf(w1.z, hv.z, gz0); gz1 = fmaf(w1.w, hv.w, gz1);
      gn0 = fmaf(w2.x, hv.x, gn0); gn1 = fmaf(w2.y, hv.y, gn1);
      gn0 = fmaf(w2.z, hv.z, gn0); gn1 = fmaf(w2.w, hv.w, gn1);
    }
    float xt = sh_x[t];
    float r = fsig(fmaf(xt, wih0, bih0) + gr0 + gr1);
    float z = fsig(fmaf(xt, wih1, bih1) + gz0 + gz1);
    float n = ftanh(fmaf(xt, wih2, bih2) + r * (gn0 + gn1));
    float hnew = fmaf(z, hprev - n, n);
    hprev = hnew;
    sh_h[l] = hnew;
    sh_h16[l] = (_Float16)hnew;
    __syncthreads();
    // Hp[t][a] incremental: lane l -> (a, half) partial via packed dot2
    {
      float acc = 0.f;
      const _Float16* hb = &sh_h16[half * 32];
      #pragma unroll
      for (int kk = 0; kk < 4; ++kk) {
        uint4 hv = *(const uint4*)&hb[kk * 8];
        acc = fdot2f(bch(hv.x), bch(sh_ud[kk * 4 + 0][l]), acc);
        acc = fdot2f(bch(hv.y), bch(sh_ud[kk * 4 + 1][l]), acc);
        acc = fdot2f(bch(hv.z), bch(sh_ud[kk * 4 + 2][l]), acc);
        acc = fdot2f(bch(hv.w), bch(sh_ud[kk * 4 + 3][l]), acc);
      }
      acc += __shfl_xor(acc, 32);                    // combine halves
      float accn = __shfl_down(acc, 1);              // neighbor a+1
      if (l < 32 && (l & 1) == 0)
        sh_hp[t][l >> 1] = __builtin_bit_cast(unsigned,
                             __builtin_amdgcn_cvt_pkrtz(acc, accn));
    }
    // hw[t] = sum_e W_out[64+e] * h_t[e]  (ctx is only ever dotted with W_out2)
    {
      float hws = wredsum(wout2 * hnew);
      if (l == 0) sh_hw[t] = hws;
    }
  }

  // ---------------- decoder prep ----------------
  float dprev;
  {  // d0 = h_T @ W_init.T + b_init
    const float4* wi = (const float4*)(W_init + l * 64);
    float a0 = b_init[l], a1 = 0.f;
    #pragma unroll
    for (int k = 0; k < 16; ++k) {
      float4 wv = wi[k];
      float4 hv = *(const float4*)&sh_h[4 * k];
      a0 = fmaf(wv.x, hv.x, a0); a1 = fmaf(wv.y, hv.y, a1);
      a0 = fmaf(wv.z, hv.z, a0); a1 = fmaf(wv.w, hv.w, a1);
    }
    dprev = a0 + a1;
    sh_d[l] = dprev;
    sh_d16[l] = (_Float16)dprev;
  }
  {  // reload wr with decoder W_hh rows
    const float4* wp = (const float4*)W_hh_d;
    #pragma unroll
    for (int k = 0; k < 16; ++k) {
      wr[k]      = wp[(l      ) * 16 + k];
      wr[16 + k] = wp[(64 + l ) * 16 + k];
      wr[32 + k] = wp[(128 + l) * 16 + k];
    }
  }
  wih0 = W_ih_d[l]; wih1 = W_ih_d[64 + l]; wih2 = W_ih_d[128 + l];
  bih0 = b_ih_d[l]; bih1 = b_ih_d[64 + l]; bih2 = b_ih_d[128 + l];
  bhh0 = b_hh_d[l]; bhh1 = b_hh_d[64 + l]; bhh2 = b_hh_d[128 + l];
  {  // W_d -> sh_ud (overwrites U_d; same 32x64 shape)
    const float2* up = (const float2*)(W_d + a * 64 + half * 32);
    #pragma unroll
    for (int k = 0; k < 16; ++k) {
      float2 f = up[k];
      sh_ud[k][l] = __builtin_bit_cast(unsigned, __builtin_amdgcn_cvt_pkrtz(f.x, f.y));
    }
  }
  float oprev = y0[0];
  float bo = b_out[0];
  __syncthreads();

  // ---------------- decoder: 24 steps, one wave ----------------
  for (int s = 0; s < HOR; ++s) {
    // GRU: gh matvec + combine, all in-lane
    float gr0 = bhh0, gr1 = 0.f, gz0 = bhh1, gz1 = 0.f, gn0 = bhh2, gn1 = 0.f;
    #pragma unroll
    for (int k = 0; k < 16; ++k) {
      float4 dv = *(const float4*)&sh_d[4 * k];
      float4 w0 = wr[k], w1 = wr[16 + k], w2 = wr[32 + k];
      gr0 = fmaf(w0.x, dv.x, gr0); gr1 = fmaf(w0.y, dv.y, gr1);
      gr0 = fmaf(w0.z, dv.z, gr0); gr1 = fmaf(w0.w, dv.w, gr1);
      gz0 = fmaf(w1.x, dv.x, gz0); gz1 = fmaf(w1.y, dv.y, gz1);
      gz0 = fmaf(w1.z, dv.z, gz0); gz1 = fmaf(w1.w, dv.w, gz1);
      gn0 = fmaf(w2.x, dv.x, gn0); gn1 = fmaf(w2.y, dv.y, gn1);
      gn0 = fmaf(w2.z, dv.z, gn0); gn1 = fmaf(w2.w, dv.w, gn1);
    }
    float r = fsig(fmaf(oprev, wih0, bih0) + gr0 + gr1);
    float z = fsig(fmaf(oprev, wih1, bih1) + gz0 + gz1);
    float n = ftanh(fmaf(oprev, wih2, bih2) + r * (gn0 + gn1));
    float dnew = fmaf(z, dprev - n, n);
    dprev = dnew;
    sh_d[l] = dnew;
    sh_d16[l] = (_Float16)dnew;
    __syncthreads();
    // d_proj[a] via packed dot2
    {
      float acc = 0.f;
      const _Float16* db = &sh_d16[half * 32];
      #pragma unroll
      for (int kk = 0; kk < 4; ++kk) {
        uint4 dv = *(const uint4*)&db[kk * 8];
        acc = fdot2f(bch(dv.x), bch(sh_ud[kk * 4 + 0][l]), acc);
        acc = fdot2f(bch(dv.y), bch(sh_ud[kk * 4 + 1][l]), acc);
        acc = fdot2f(bch(dv.z), bch(sh_ud[kk * 4 + 2][l]), acc);
        acc = fdot2f(bch(dv.w), bch(sh_ud[kk * 4 + 3][l]), acc);
      }
      acc += __shfl_xor(acc, 32);
      if (l < 32) sh_dp[l] = acc;
    }
    __syncthreads();
    // scores for rows t0=l, t1=64+l (no max-sub: |s| <= sum|v_d| ~ 2.6)
    float4 dpv[8];
    #pragma unroll
    for (int k = 0; k < 8; ++k) dpv[k] = *(const float4*)&sh_dp[4 * k];
    float s0 = 0.f, s1 = 0.f;
    #pragma unroll
    for (int j = 0; j < 16; ++j) {
      float4 q = dpv[j >> 1];
      float dpa = (j & 1) ? q.z : q.x;
      float dpb = (j & 1) ? q.w : q.y;
      half2_t h0 = bch(sh_hp[l][j]);
      half2_t h1 = bch(sh_hp[64 + l][j]);
      float va = v_d[2 * j], vb = v_d[2 * j + 1];
      s0 = fmaf(ftanh(dpa + (float)h0.x), va, s0);
      s0 = fmaf(ftanh(dpb + (float)h0.y), vb, s0);
      s1 = fmaf(ftanh(dpa + (float)h1.x), va, s1);
      s1 = fmaf(ftanh(dpb + (float)h1.y), vb, s1);
    }
    float e0 = fexp(s0), e1 = fexp(s1);
    float hw0 = sh_hw[l], hw1 = sh_hw[64 + l];
    float Asum = wredsum(e0 + e1);                       // softmax denom
    float Bsum = wredsum(fmaf(e0, hw0, e1 * hw1));       // sum_t e_t * hw[t]
    float Csum = wredsum(wout1 * dnew);                  // W_out1 . d
    float o = fmaf(Bsum, __builtin_amdgcn_rcpf(Asum), Csum + bo);
    if (l == 0) out[(size_t)b * HOR + s] = o;
    oprev = o;
  }
}

extern "C" void kernel_launch(void* const* d_in, const int* in_sizes, int n_in,
                              void* d_out, int out_size, void* d_ws, size_t ws_size,
                              hipStream_t stream) {
  const float* x      = (const float*)d_in[0];
  const float* W_ih_e = (const float*)d_in[1];
  const float* W_hh_e = (const float*)d_in[2];
  const float* b_ih_e = (const float*)d_in[3];
  const float* b_hh_e = (const float*)d_in[4];
  // d_in[5..8] = W_e, U_e, b_e, v_e : dead (softmax over size-1 axis == 1)
  const float* W_init = (const float*)d_in[9];
  const float* b_init = (const float*)d_in[10];
  const float* W_ih_d = (const float*)d_in[11];
  const float* W_hh_d = (const float*)d_in[12];
  const float* b_ih_d = (const float*)d_in[13];
  const float* b_hh_d = (const float*)d_in[14];
  const float* W_d    = (const float*)d_in[15];
  const float* U_d    = (const float*)d_in[16];
  const float* v_d    = (const float*)d_in[17];
  const float* W_out  = (const float*)d_in[18];
  const float* b_out  = (const float*)d_in[19];
  const float* y0     = (const float*)d_in[20];
  float* outp = (float*)d_out;

  darnn_kernel<<<BATCH, 64, 0, stream>>>(x, W_ih_e, W_hh_e, b_ih_e, b_hh_e,
      W_init, b_init, W_ih_d, W_hh_d, b_ih_d, b_hh_d, W_d, U_d, v_d, W_out,
      b_out, y0, outp);
}

// Round 4
// 505.103 us; speedup vs baseline: 3.5837x; 1.0978x over previous
//
#include <hip/hip_runtime.h>
#include <math.h>

#define BATCH 4096
#define T 128
#define HOR 24
#define HPAD 20

#define LOG2E 1.44269504088896f
#define C2    2.88539008177793f   // 2*log2(e)

typedef _Float16 half2_t __attribute__((ext_vector_type(2)));
typedef float f2  __attribute__((ext_vector_type(2)));
typedef float f4v __attribute__((ext_vector_type(4)));

__device__ __forceinline__ float fexp2(float x){ return __builtin_amdgcn_exp2f(x); }
__device__ __forceinline__ float frcp(float x){ return __builtin_amdgcn_rcpf(x); }
__device__ __forceinline__ float fsig(float x){ return frcp(1.0f + fexp2(-LOG2E*x)); }
__device__ __forceinline__ float ftanh(float x){ return fmaf(-2.0f, frcp(1.0f + fexp2(C2*x)), 1.0f); }
__device__ __forceinline__ half2_t bch(unsigned u){ return __builtin_bit_cast(half2_t,u); }
__device__ __forceinline__ unsigned pk2(float a,float b){ return __builtin_bit_cast(unsigned, __builtin_amdgcn_cvt_pkrtz(a,b)); }
__device__ __forceinline__ float fdot2f(half2_t a, half2_t b, float c){
#if __has_builtin(__builtin_amdgcn_fdot2)
  return __builtin_amdgcn_fdot2(a,b,c,false);
#else
  return fmaf((float)a.x,(float)b.x, fmaf((float)a.y,(float)b.y,c));
#endif
}
__device__ __forceinline__ f2 pkfma(f2 a, f2 b, f2 c){ return __builtin_elementwise_fma(a,b,c); }

// One wave per batch element; lane l owns h[l]/d[l] and GRU rows l,64+l,128+l.
__global__ __launch_bounds__(64, 2)
void darnn_kernel(const float* __restrict__ x,
                  const float* __restrict__ W_ih_e, const float* __restrict__ W_hh_e,
                  const float* __restrict__ b_ih_e, const float* __restrict__ b_hh_e,
                  const float* __restrict__ W_init, const float* __restrict__ b_init,
                  const float* __restrict__ W_ih_d, const float* __restrict__ W_hh_d,
                  const float* __restrict__ b_ih_d, const float* __restrict__ b_hh_d,
                  const float* __restrict__ W_d, const float* __restrict__ U_d,
                  const float* __restrict__ v_d, const float* __restrict__ W_out,
                  const float* __restrict__ b_out, const float* __restrict__ y0,
                  float* __restrict__ out)
{
  const int l = threadIdx.x;            // 0..63
  const int b = blockIdx.x;
  const int a    = l & 31;
  const int half = l >> 5;

  __shared__ __align__(16) float     sh_ring[8][68];     // h ring fp32 (rows 16B-aligned)
  __shared__ __align__(16) _Float16  sh_h16[64];         // h (later d) fp16
  __shared__ __align__(16) float     sh_x[T];
  __shared__ __align__(16) float     sh_hw[T];           // hw[t] = W_out2 . h_t
  __shared__ __align__(16) unsigned  sh_hp[T*HPAD];      // Hp fp16-packed, pre-scaled by C2
  __shared__ __align__(16) unsigned  sh_ud[16][64];      // U_d (later W_d) half2
  __shared__ __align__(16) float     sh_dp[32];          // d_proj, pre-scaled by C2
  __shared__ __align__(16) float     sh_wo2[64];         // W_out[64..127]

  unsigned wr_r[32], wr_z[32];          // r/z rows packed fp16 (64 VGPRs)
  f4v      wn[16];                      // n row fp32 (64 VGPRs)

  // ---------------- stage ----------------
  {
    const f4v* wp = (const f4v*)W_hh_e;
    #pragma unroll
    for (int k = 0; k < 16; ++k) {
      f4v ar = wp[l*16 + k];
      f4v az = wp[(64 + l)*16 + k];
      wr_r[2*k] = pk2(ar.x, ar.y); wr_r[2*k+1] = pk2(ar.z, ar.w);
      wr_z[2*k] = pk2(az.x, az.y); wr_z[2*k+1] = pk2(az.z, az.w);
      wn[k] = wp[(128 + l)*16 + k];
    }
  }
  float wih0 = W_ih_e[l], wih1 = W_ih_e[64+l], wih2 = W_ih_e[128+l];
  float bb0  = b_ih_e[l] + b_hh_e[l];
  float bb1  = b_ih_e[64+l] + b_hh_e[64+l];
  float bih2 = b_ih_e[128+l], bhh2 = b_hh_e[128+l];
  float wout1 = W_out[l];
  sh_wo2[l] = W_out[64 + l];
  {
    f2 g = ((const f2*)(x + (size_t)b * T))[l];
    sh_x[2*l] = g.x; sh_x[2*l+1] = g.y;
  }
  sh_ring[7][l] = 0.0f;                 // h_{-1} = 0 (step 0 reads row 7)
  sh_h16[l] = (_Float16)0.0f;
  {  // U_d -> sh_ud[k][lane]
    const f2* up = (const f2*)(U_d + a*64 + half*32);
    #pragma unroll
    for (int k = 0; k < 16; ++k) {
      f2 f = up[k];
      sh_ud[k][l] = pk2(f.x, f.y);
    }
  }
  __syncthreads();

  // ---------------- encoder: 128 steps ----------------
  // input-attention is identity (softmax over size-1 axis == 1).
  float hprev = 0.0f;
  for (int t0 = 0; t0 < T; t0 += 8) {
    #pragma unroll
    for (int u = 0; u < 8; ++u) {
      const int t = t0 + u;
      const int rprev = (t + 7) & 7;
      // r,z gates: fp16 dot2 against sh_h16
      float ar0=0.f, ar1=0.f, az0=0.f, az1=0.f;
      {
        const uint4* hq = (const uint4*)sh_h16;
        #pragma unroll
        for (int q = 0; q < 8; ++q) {
          uint4 hv = hq[q];
          ar0 = fdot2f(bch(hv.x), bch(wr_r[4*q+0]), ar0);
          az0 = fdot2f(bch(hv.x), bch(wr_z[4*q+0]), az0);
          ar1 = fdot2f(bch(hv.y), bch(wr_r[4*q+1]), ar1);
          az1 = fdot2f(bch(hv.y), bch(wr_z[4*q+1]), az1);
          ar0 = fdot2f(bch(hv.z), bch(wr_r[4*q+2]), ar0);
          az0 = fdot2f(bch(hv.z), bch(wr_z[4*q+2]), az0);
          ar1 = fdot2f(bch(hv.w), bch(wr_r[4*q+3]), ar1);
          az1 = fdot2f(bch(hv.w), bch(wr_z[4*q+3]), az1);
        }
      }
      // n gate: fp32 packed fma against ring
      f2 n0 = {0.f,0.f}, n1 = {0.f,0.f};
      {
        const f4v* hb = (const f4v*)sh_ring[rprev];
        #pragma unroll
        for (int k = 0; k < 16; ++k) {
          f4v hv = hb[k];
          n0 = pkfma(wn[k].xy, hv.xy, n0);
          n1 = pkfma(wn[k].zw, hv.zw, n1);
        }
      }
      float xt = sh_x[t];
      float r = fsig(fmaf(xt, wih0, bb0) + ar0 + ar1);
      float z = fsig(fmaf(xt, wih1, bb1) + az0 + az1);
      float gn = (n0.x + n0.y) + (n1.x + n1.y) + bhh2;
      float n = ftanh(fmaf(xt, wih2, bih2) + r * gn);
      float hnew = fmaf(z, hprev - n, n);
      hprev = hnew;
      sh_ring[t & 7][l] = hnew;
      sh_h16[l] = (_Float16)hnew;
      __syncthreads();
      // Hp[t][a] pre-scaled by C2, packed to fp16
      {
        float acc = 0.f;
        const uint4* hb16 = (const uint4*)(sh_h16 + 32*half);
        #pragma unroll
        for (int kk = 0; kk < 4; ++kk) {
          uint4 hv = hb16[kk];
          acc = fdot2f(bch(hv.x), bch(sh_ud[kk*4+0][l]), acc);
          acc = fdot2f(bch(hv.y), bch(sh_ud[kk*4+1][l]), acc);
          acc = fdot2f(bch(hv.z), bch(sh_ud[kk*4+2][l]), acc);
          acc = fdot2f(bch(hv.w), bch(sh_ud[kk*4+3][l]), acc);
        }
        acc += __shfl_xor(acc, 32);
        acc *= C2;
        float accn = __shfl_down(acc, 1);
        if (l < 32 && !(l & 1))
          sh_hp[t*HPAD + (l >> 1)] = pk2(acc, accn);
      }
      // hw batch every 8 steps: hw[t-7..t]
      if ((t & 7) == 7) {
        int r8 = l >> 3, c8 = l & 7;
        float p = 0.f;
        #pragma unroll
        for (int j = 0; j < 8; ++j)
          p = fmaf(sh_wo2[8*c8 + j], sh_ring[r8][8*c8 + j], p);
        p += __shfl_xor(p, 1);
        p += __shfl_xor(p, 2);
        p += __shfl_xor(p, 4);
        if (c8 == 0) sh_hw[t - 7 + r8] = p;
      }
    }
  }

  // ---------------- decoder prep ----------------
  float dprev;
  {  // d0 = h_T @ W_init.T + b_init (h_T is in sh_ring[7])
    const f4v* wi = (const f4v*)(W_init + l*64);
    const f4v* hb = (const f4v*)sh_ring[7];
    f2 a0 = {0.f,0.f}, a1 = {0.f,0.f};
    #pragma unroll
    for (int k = 0; k < 16; ++k) {
      f4v wv = wi[k]; f4v hv = hb[k];
      a0 = pkfma(wv.xy, hv.xy, a0);
      a1 = pkfma(wv.zw, hv.zw, a1);
    }
    dprev = b_init[l] + (a0.x + a0.y) + (a1.x + a1.y);
  }
  {  // reload GRU weights with decoder W_hh
    const f4v* wp = (const f4v*)W_hh_d;
    #pragma unroll
    for (int k = 0; k < 16; ++k) {
      f4v ar = wp[l*16 + k];
      f4v az = wp[(64 + l)*16 + k];
      wr_r[2*k] = pk2(ar.x, ar.y); wr_r[2*k+1] = pk2(ar.z, ar.w);
      wr_z[2*k] = pk2(az.x, az.y); wr_z[2*k+1] = pk2(az.z, az.w);
      wn[k] = wp[(128 + l)*16 + k];
    }
  }
  wih0 = W_ih_d[l]; wih1 = W_ih_d[64+l]; wih2 = W_ih_d[128+l];
  bb0  = b_ih_d[l] + b_hh_d[l];
  bb1  = b_ih_d[64+l] + b_hh_d[64+l];
  bih2 = b_ih_d[128+l]; bhh2 = b_hh_d[128+l];
  {  // W_d -> sh_ud (overwrites U_d)
    const f2* up = (const f2*)(W_d + a*64 + half*32);
    #pragma unroll
    for (int k = 0; k < 16; ++k) {
      f2 f = up[k];
      sh_ud[k][l] = pk2(f.x, f.y);
    }
  }
  sh_ring[0][l] = dprev;                // d lives in ring row 0
  sh_h16[l] = (_Float16)dprev;
  float oprev = y0[0];
  float bo = b_out[0];
  // SV = sum(v_d); c1 = log2e*SV (all lanes)
  float c1;
  {
    float sv = v_d[a];
    sv += __shfl_xor(sv, 16); sv += __shfl_xor(sv, 8);
    sv += __shfl_xor(sv, 4);  sv += __shfl_xor(sv, 2); sv += __shfl_xor(sv, 1);
    c1 = LOG2E * sv;
  }
  __syncthreads();
  // hp rows t=l and t=64+l -> registers (pre-scaled, packed)
  unsigned hp0[16], hp1[16];
  #pragma unroll
  for (int j = 0; j < 16; ++j) {
    hp0[j] = sh_hp[l*HPAD + j];
    hp1[j] = sh_hp[(64 + l)*HPAD + j];
  }
  float hw0 = sh_hw[l], hw1 = sh_hw[64 + l];

  // ---------------- decoder: 24 steps ----------------
  for (int s = 0; s < HOR; ++s) {
    // GRU matvec + combine
    float ar0=0.f, ar1=0.f, az0=0.f, az1=0.f;
    {
      const uint4* hq = (const uint4*)sh_h16;
      #pragma unroll
      for (int q = 0; q < 8; ++q) {
        uint4 hv = hq[q];
        ar0 = fdot2f(bch(hv.x), bch(wr_r[4*q+0]), ar0);
        az0 = fdot2f(bch(hv.x), bch(wr_z[4*q+0]), az0);
        ar1 = fdot2f(bch(hv.y), bch(wr_r[4*q+1]), ar1);
        az1 = fdot2f(bch(hv.y), bch(wr_z[4*q+1]), az1);
        ar0 = fdot2f(bch(hv.z), bch(wr_r[4*q+2]), ar0);
        az0 = fdot2f(bch(hv.z), bch(wr_z[4*q+2]), az0);
        ar1 = fdot2f(bch(hv.w), bch(wr_r[4*q+3]), ar1);
        az1 = fdot2f(bch(hv.w), bch(wr_z[4*q+3]), az1);
      }
    }
    f2 n0 = {0.f,0.f}, n1 = {0.f,0.f};
    {
      const f4v* db = (const f4v*)sh_ring[0];
      #pragma unroll
      for (int k = 0; k < 16; ++k) {
        f4v dv = db[k];
        n0 = pkfma(wn[k].xy, dv.xy, n0);
        n1 = pkfma(wn[k].zw, dv.zw, n1);
      }
    }
    float r = fsig(fmaf(oprev, wih0, bb0) + ar0 + ar1);
    float z = fsig(fmaf(oprev, wih1, bb1) + az0 + az1);
    float gn = (n0.x + n0.y) + (n1.x + n1.y) + bhh2;
    float n = ftanh(fmaf(oprev, wih2, bih2) + r * gn);
    float dnew = fmaf(z, dprev - n, n);
    dprev = dnew;
    sh_ring[0][l] = dnew;
    sh_h16[l] = (_Float16)dnew;
    __syncthreads();
    // d_proj[a], pre-scaled by C2
    {
      float acc = 0.f;
      const uint4* db16 = (const uint4*)(sh_h16 + 32*half);
      #pragma unroll
      for (int kk = 0; kk < 4; ++kk) {
        uint4 dv = db16[kk];
        acc = fdot2f(bch(dv.x), bch(sh_ud[kk*4+0][l]), acc);
        acc = fdot2f(bch(dv.y), bch(sh_ud[kk*4+1][l]), acc);
        acc = fdot2f(bch(dv.z), bch(sh_ud[kk*4+2][l]), acc);
        acc = fdot2f(bch(dv.w), bch(sh_ud[kk*4+3][l]), acc);
      }
      acc += __shfl_xor(acc, 32);
      if (l < 32) sh_dp[l] = C2 * acc;
    }
    __syncthreads();
    // scores rows t0=l, t1=64+l: score = SV - 2*sum_a v_a * r_a,
    // r_a = 1/(1+exp2(dps_a + hps_a)) (both pre-scaled by 2*log2e)
    float rs0 = 0.f, rs1 = 0.f;
    #pragma unroll
    for (int j2 = 0; j2 < 8; ++j2) {
      f4v dp = *(const f4v*)&sh_dp[4*j2];
      half2_t ha0 = bch(hp0[2*j2]),   hb0 = bch(hp0[2*j2+1]);
      half2_t ha1 = bch(hp1[2*j2]),   hb1 = bch(hp1[2*j2+1]);
      float v0 = v_d[4*j2], v1 = v_d[4*j2+1], v2 = v_d[4*j2+2], v3 = v_d[4*j2+3];
      rs0 = fmaf(v0, frcp(1.0f + fexp2(dp.x + (float)ha0.x)), rs0);
      rs0 = fmaf(v1, frcp(1.0f + fexp2(dp.y + (float)ha0.y)), rs0);
      rs0 = fmaf(v2, frcp(1.0f + fexp2(dp.z + (float)hb0.x)), rs0);
      rs0 = fmaf(v3, frcp(1.0f + fexp2(dp.w + (float)hb0.y)), rs0);
      rs1 = fmaf(v0, frcp(1.0f + fexp2(dp.x + (float)ha1.x)), rs1);
      rs1 = fmaf(v1, frcp(1.0f + fexp2(dp.y + (float)ha1.y)), rs1);
      rs1 = fmaf(v2, frcp(1.0f + fexp2(dp.z + (float)hb1.x)), rs1);
      rs1 = fmaf(v3, frcp(1.0f + fexp2(dp.w + (float)hb1.y)), rs1);
    }
    float e0 = fexp2(fmaf(-C2, rs0, c1));   // exp(score_t0)
    float e1 = fexp2(fmaf(-C2, rs1, c1));
    // three interleaved wave reductions
    float p0 = e0 + e1;
    float p1 = fmaf(e0, hw0, e1 * hw1);
    float p2 = wout1 * dnew;
    #pragma unroll
    for (int off = 32; off > 0; off >>= 1) {
      p0 += __shfl_xor(p0, off);
      p1 += __shfl_xor(p1, off);
      p2 += __shfl_xor(p2, off);
    }
    float o = fmaf(p1, frcp(p0), p2 + bo);
    if (l == 0) out[(size_t)b * HOR + s] = o;
    oprev = o;
  }
}

extern "C" void kernel_launch(void* const* d_in, const int* in_sizes, int n_in,
                              void* d_out, int out_size, void* d_ws, size_t ws_size,
                              hipStream_t stream) {
  const float* x      = (const float*)d_in[0];
  const float* W_ih_e = (const float*)d_in[1];
  const float* W_hh_e = (const float*)d_in[2];
  const float* b_ih_e = (const float*)d_in[3];
  const float* b_hh_e = (const float*)d_in[4];
  // d_in[5..8] = W_e, U_e, b_e, v_e : dead (softmax over size-1 axis == 1)
  const float* W_init = (const float*)d_in[9];
  const float* b_init = (const float*)d_in[10];
  const float* W_ih_d = (const float*)d_in[11];
  const float* W_hh_d = (const float*)d_in[12];
  const float* b_ih_d = (const float*)d_in[13];
  const float* b_hh_d = (const float*)d_in[14];
  const float* W_d    = (const float*)d_in[15];
  const float* U_d    = (const float*)d_in[16];
  const float* v_d    = (const float*)d_in[17];
  const float* W_out  = (const float*)d_in[18];
  const float* b_out  = (const float*)d_in[19];
  const float* y0     = (const float*)d_in[20];
  float* outp = (float*)d_out;

  darnn_kernel<<<BATCH, 64, 0, stream>>>(x, W_ih_e, W_hh_e, b_ih_e, b_hh_e,
      W_init, b_init, W_ih_d, W_hh_d, b_ih_d, b_hh_d, W_d, U_d, v_d, W_out,
      b_out, y0, outp);
}